// Round 5
// baseline (1096.945 us; speedup 1.0000x reference)
//
#include <hip/hip_runtime.h>

typedef unsigned short u16;
typedef __attribute__((ext_vector_type(8))) short bfrag8;     // 8 bf16 = 4 VGPR (MFMA A/B frag)
typedef __attribute__((ext_vector_type(4))) float fvec4;      // MFMA C/D frag
typedef __attribute__((ext_vector_type(4))) unsigned short usvec4;

// ---- problem constants ----
#define Bc   16
#define Nn   10000
#define Rr   10
#define Ss   1000
#define Gg   4
#define SP   1024      // K-padded S
#define MP   1024      // M-padded S (An rows padded with zeros)
#define NPAD 10048     // padded node count for inpT / hwcT

__device__ __forceinline__ float bf2f(u16 u) {
  union { unsigned int i; float f; } x; x.i = ((unsigned int)u) << 16; return x.f;
}
__device__ __forceinline__ u16 f2bf(float f) {
  unsigned int x = __float_as_uint(f);
  unsigned int r = x + 0x7FFFu + ((x >> 16) & 1u);   // RNE; no NaNs in this workload
  return (u16)(r >> 16);
}

// async global->LDS, 16B per lane; dest = wave-uniform base + lane*16
__device__ __forceinline__ void glds16(const u16* gsrc, u16* ldst) {
  __builtin_amdgcn_global_load_lds((const __attribute__((address_space(1))) unsigned int*)gsrc,
                                   (__attribute__((address_space(3))) unsigned int*)ldst, 16, 0, 0);
}

// stage a [nloads*8 rows][64 k] bf16 tile: linear LDS dest, source pre-swizzled so that
// reads with byte ^= ((row&7)<<4) are conflict-free.
__device__ __forceinline__ void stage_tile(const u16* gsrc, size_t rstride, int nloads,
                                           u16* ldsbase, int wid, int lane) {
  int rsub = lane >> 3;
  int kb8 = ((lane & 7) ^ rsub) << 3;          // swizzled k-offset in u16 (chunk*8)
  for (int i = wid; i < nloads; i += 4)
    glds16(gsrc + (size_t)(8 * i + rsub) * rstride + kb8, ldsbase + i * 512);
}

// swizzled fragment read from a [rows][64 k] tile (kbyte = ks*64 + hi*16)
__device__ __forceinline__ bfrag8 ldsw(const u16* base, int row, int kbyte) {
  int off = row * 128 + (kbyte ^ ((row & 7) << 4));
  return *(const bfrag8*)((const char*)base + off);
}

// ---------------- K0: weight prep ----------------
__global__ __launch_bounds__(256) void prep_weights_kernel(
    const float* __restrict__ Wu, const float* __restrict__ Wr, const float* __restrict__ Wc,
    const float* __restrict__ a1u, const float* __restrict__ a1r, const float* __restrict__ a1c,
    u16* __restrict__ Wt, u16* __restrict__ a1wb, u16* __restrict__ a1wT)
{
  int idx = blockIdx.x * 256 + threadIdx.x;
  if (idx < 73728) {                       // Wt[p][g][e][d] = W[g][d][e]
    int p = idx / 24576, rem = idx % 24576;
    int g = rem / 6144, r2 = rem % 6144;
    int e = r2 / 96, dd = r2 % 96;
    const float* W = (p == 0) ? Wu : (p == 1) ? Wr : Wc;
    Wt[idx] = f2bf(W[(g * 96 + dd) * 64 + e]);
  } else if (idx < 73728 + 49536) {        // a1wb[p][k][e] (k<258)
    int j = idx - 73728;
    int p = j / 16512, k = j % 16512;
    const float* s = (p == 0) ? a1u : (p == 1) ? a1r : a1c;
    a1wb[j] = f2bf(s[k]);
  } else if (idx < 73728 + 49536 + 49152) {// a1wT[p][e][k] = a1w[k][e], k<256
    int j = idx - 123264;
    int p = j / 16384, rem = j % 16384;
    int e = rem / 256, k = rem % 256;
    const float* s = (p == 0) ? a1u : (p == 1) ? a1r : a1c;
    a1wT[j] = f2bf(s[k * 64 + e]);
  }
}

// ---------------- K1: row sums -> deg^-0.5 ----------------
__global__ __launch_bounds__(256) void rowsum_kernel(const float* __restrict__ A,
                                                     float* __restrict__ dis)
{
  int wid = threadIdx.x >> 6, lane = threadIdx.x & 63;
  int row = blockIdx.x * 4 + wid;          // 40000 rows
  const float* ap = A + (size_t)row * 1000;
  float s = 0.f;
  for (int i = lane; i < 250; i += 64) {
    float4 v = *(const float4*)(ap + i * 4);
    s += (v.x + v.y) + (v.z + v.w);
  }
  #pragma unroll
  for (int off = 32; off >= 1; off >>= 1) s += __shfl_xor(s, off);
  if (lane == 0) dis[row] = rsqrtf(fmaxf(s, 1e-5f));
}

// ---------------- K2: build An (bf16, K padded to 1024, M padded to 1024 with zero rows) ----
__global__ __launch_bounds__(256) void build_an_kernel(const float* __restrict__ A,
                                                       const float* __restrict__ dis,
                                                       u16* __restrict__ An)
{
  int gr = blockIdx.x >> 10, s = blockIdx.x & 1023;
  u16* anp = An + (size_t)blockIdx.x * 1024;      // (gr*1024+s)*1024
  int t4 = threadIdx.x * 4;
  if (s >= Ss || t4 >= 1000) {
    usvec4 z = {0, 0, 0, 0};
    *(usvec4*)(anp + t4) = z;
    return;
  }
  int rowid = gr * 1000 + s;
  float ds = dis[rowid];
  const float* ap = A + (size_t)rowid * 1000;
  float4 a4 = *(const float4*)(ap + t4);
  float4 d4 = *(const float4*)(dis + gr * 1000 + t4);
  float v0 = ds * d4.x * (a4.x + ((t4 + 0) == s ? 1.f : 0.f));
  float v1 = ds * d4.y * (a4.y + ((t4 + 1) == s ? 1.f : 0.f));
  float v2 = ds * d4.z * (a4.z + ((t4 + 2) == s ? 1.f : 0.f));
  float v3 = ds * d4.w * (a4.w + ((t4 + 3) == s ? 1.f : 0.f));
  usvec4 o = {f2bf(v0), f2bf(v1), f2bf(v2), f2bf(v3)};
  *(usvec4*)(anp + t4) = o;
}

// ---------------- K3: inp prep -> inpT[b][d][n] (d-major) + candb x-part [t][0..31] ------
__global__ __launch_bounds__(256) void prep_inpT_kernel(const float* __restrict__ x_t,
                                                        const float* __restrict__ h_prev,
                                                        u16* __restrict__ inpT,
                                                        u16* __restrict__ candb)
{
  int b = blockIdx.y, n0 = blockIdx.x * 64;
  __shared__ float t[64][97];
  for (int idx = threadIdx.x; idx < 2048; idx += 256) {
    int ni = idx >> 5, d = idx & 31;
    int n = n0 + ni;
    t[ni][d] = (n < Nn) ? x_t[(size_t)(b * Nn + n) * 32 + d] : 0.f;
  }
  for (int idx = threadIdx.x; idx < 4096; idx += 256) {
    int ni = idx >> 6, d = idx & 63;
    int n = n0 + ni;
    t[ni][32 + d] = (n < Nn) ? h_prev[(size_t)(b * Nn + n) * 64 + d] : 0.f;
  }
  __syncthreads();
  for (int idx = threadIdx.x; idx < 6144; idx += 256) {
    int d = idx >> 6, ni = idx & 63;
    inpT[(size_t)b * (96 * NPAD) + (size_t)d * NPAD + n0 + ni] = f2bf(t[ni][d]);
  }
  for (int idx = threadIdx.x; idx < 2048; idx += 256) {
    int ni = idx >> 5, d = idx & 31;
    int n = n0 + ni;
    if (n < Nn) candb[((size_t)b * Nn + n) * 96 + d] = f2bf(t[ni][d]);
  }
}

// ---------------- K4: GEMM1  Ai = An @ inp, then project to U,R (fused epilogue) ---------
// grid (8 mt, 8 bp, 40 gr), 256 thr (4 waves 2x2), tile 128x192 (2 batches), BK=64
__global__ __launch_bounds__(256) void gemm_uv_kernel(
    const u16* __restrict__ An,     // [40][1024][1024]
    const u16* __restrict__ inpT,   // [16*96 rows=(b,d)][NPAD]
    const u16* __restrict__ Wt,     // [3][4][64][96]
    u16* __restrict__ outs0, u16* __restrict__ outs1)
{
  __shared__ __align__(1024) u16 lds[20480];   // A 8192 + B 12288 @8192; epi reuse [128][104]

  const int tid = threadIdx.x, lane = tid & 63, wid = tid >> 6;
  const int mt = blockIdx.x, bp = blockIdx.y, gr = blockIdx.z;
  const int g = gr / Rr, r = gr % Rr;
  const int m0 = mt * 128;
  const int wrow0 = (wid >> 1) * 64, wcol0 = (wid & 1) * 96;
  const int lr = lane & 15, hi = lane >> 4;
  const int kbhi = hi * 16;

  const u16* Ap = An + (size_t)gr * (MP * SP) + (size_t)m0 * SP;
  const u16* Bp = inpT + (size_t)(bp * 192) * NPAD + r * Ss;

  fvec4 acc[4][6];
  #pragma unroll
  for (int i = 0; i < 4; ++i)
    #pragma unroll
    for (int j = 0; j < 6; ++j) acc[i][j] = (fvec4){0.f, 0.f, 0.f, 0.f};

  #pragma unroll 1
  for (int kt = 0; kt < 16; ++kt) {
    const int kk = kt * 64;
    __syncthreads();
    stage_tile(Ap + kk, SP, 16, lds, wid, lane);
    stage_tile(Bp + kk, NPAD, 24, lds + 8192, wid, lane);
    __syncthreads();
    #pragma unroll
    for (int ks = 0; ks < 2; ++ks) {
      bfrag8 a[4], bb[6];
      #pragma unroll
      for (int mfi = 0; mfi < 4; ++mfi) a[mfi] = ldsw(lds, wrow0 + mfi * 16 + lr, ks * 64 + kbhi);
      #pragma unroll
      for (int nfi = 0; nfi < 6; ++nfi) bb[nfi] = ldsw(lds + 8192, wcol0 + nfi * 16 + lr, ks * 64 + kbhi);
      #pragma unroll
      for (int mfi = 0; mfi < 4; ++mfi)
        #pragma unroll
        for (int nfi = 0; nfi < 6; ++nfi)
          acc[mfi][nfi] = __builtin_amdgcn_mfma_f32_16x16x32_bf16(a[mfi], bb[nfi], acc[mfi][nfi], 0, 0, 0);
    }
  }

  // epilogue: per batch-half bh (waves with (wid&1)==bh own that half's acc)
  const int s2r0 = wid * 32;
  #pragma unroll 1
  for (int bh = 0; bh < 2; ++bh) {
    __syncthreads();                                   // LDS free for bounce
    if ((wid & 1) == bh) {
      #pragma unroll
      for (int mfi = 0; mfi < 4; ++mfi)
        #pragma unroll
        for (int nfi = 0; nfi < 6; ++nfi)
          #pragma unroll
          for (int j = 0; j < 4; ++j) {
            int row = wrow0 + mfi * 16 + hi * 4 + j;
            int col = nfi * 16 + lr;
            lds[row * 104 + col] = f2bf(acc[mfi][nfi][j]);
          }
    }
    __syncthreads();

    const int b = bp * 2 + bh;
    const int obase = ((g * Bc + b) * Nn + r * Ss) * 64;
    #pragma unroll
    for (int p = 0; p < 2; ++p) {
      const u16* Wg = Wt + (size_t)(p * Gg + g) * 6144;    // [64 e][96 d]
      fvec4 acc2[2][4];
      #pragma unroll
      for (int i = 0; i < 2; ++i)
        #pragma unroll
        for (int j = 0; j < 4; ++j) acc2[i][j] = (fvec4){0.f, 0.f, 0.f, 0.f};
      #pragma unroll
      for (int dk = 0; dk < 3; ++dk) {
        bfrag8 x0 = *(const bfrag8*)&lds[(s2r0 + lr) * 104 + dk * 32 + kbhi / 2];
        bfrag8 x1 = *(const bfrag8*)&lds[(s2r0 + 16 + lr) * 104 + dk * 32 + kbhi / 2];
        #pragma unroll
        for (int ef = 0; ef < 4; ++ef) {
          bfrag8 wv = *(const bfrag8*)&Wg[(ef * 16 + lr) * 96 + dk * 32 + kbhi / 2];
          acc2[0][ef] = __builtin_amdgcn_mfma_f32_16x16x32_bf16(x0, wv, acc2[0][ef], 0, 0, 0);
          acc2[1][ef] = __builtin_amdgcn_mfma_f32_16x16x32_bf16(x1, wv, acc2[1][ef], 0, 0, 0);
        }
      }
      u16* op = (p == 0) ? outs0 : outs1;
      #pragma unroll
      for (int mf = 0; mf < 2; ++mf)
        #pragma unroll
        for (int ef = 0; ef < 4; ++ef)
          #pragma unroll
          for (int j = 0; j < 4; ++j) {
            int srow = m0 + s2r0 + mf * 16 + hi * 4 + j;
            if (srow < Ss) {
              float v = fmaxf(acc2[mf][ef][j], 0.f);
              op[obase + srow * 64 + ef * 16 + lr] = f2bf(v);
            }
          }
    }
  }
}

// ---------------- K7: cand projection  hwcT[g][b][e][n] = (cand @ W_c)^T ----------------
// grid (157, 16), 256 thr, 4 waves = 4 g; per block: 64 n-rows
__global__ __launch_bounds__(256) void cand_proj_kernel(const u16* __restrict__ candb,
                                                        const u16* __restrict__ Wt,
                                                        u16* __restrict__ hwcT)
{
  __shared__ __align__(16) u16 lds[16384];     // 4 waves x [64 e][64 t]
  const int tid = threadIdx.x, lane = tid & 63, g = tid >> 6;
  const int lr = lane & 15, hi = lane >> 4;
  const int b = blockIdx.y, n0 = blockIdx.x * 64;
  const u16* WcT = Wt + (size_t)(2 * Gg + g) * 6144;   // [64 e][96 d]

  fvec4 acc[4][4];
  #pragma unroll
  for (int i = 0; i < 4; ++i)
    #pragma unroll
    for (int j = 0; j < 4; ++j) acc[i][j] = (fvec4){0.f, 0.f, 0.f, 0.f};

  #pragma unroll
  for (int ks = 0; ks < 3; ++ks) {
    bfrag8 a[4], w[4];
    #pragma unroll
    for (int mfi = 0; mfi < 4; ++mfi)
      a[mfi] = *(const bfrag8*)&candb[((size_t)b * Nn + n0 + mfi * 16 + lr) * 96 + ks * 32 + hi * 8];
    #pragma unroll
    for (int nfi = 0; nfi < 4; ++nfi)
      w[nfi] = *(const bfrag8*)&WcT[(nfi * 16 + lr) * 96 + ks * 32 + hi * 8];
    #pragma unroll
    for (int mfi = 0; mfi < 4; ++mfi)
      #pragma unroll
      for (int nfi = 0; nfi < 4; ++nfi)
        acc[mfi][nfi] = __builtin_amdgcn_mfma_f32_16x16x32_bf16(a[mfi], w[nfi], acc[mfi][nfi], 0, 0, 0);
  }

  // bounce to LDS [e][t] per wave, then coalesced transposed store
  #pragma unroll
  for (int mfi = 0; mfi < 4; ++mfi)
    #pragma unroll
    for (int nfi = 0; nfi < 4; ++nfi)
      #pragma unroll
      for (int j = 0; j < 4; ++j) {
        int e = nfi * 16 + lr, tl = mfi * 16 + hi * 4 + j;
        lds[g * 4096 + e * 64 + tl] = f2bf(acc[mfi][nfi][j]);
      }
  __syncthreads();
  #pragma unroll
  for (int i = 0; i < 8; ++i) {
    int e = i * 8 + (lane >> 3), tc = lane & 7;
    bfrag8 v = *(const bfrag8*)&lds[g * 4096 + e * 64 + tc * 8];
    *(bfrag8*)&hwcT[((size_t)g * 1024 + b * 64 + e) * NPAD + n0 + tc * 8] = v;
  }
}

// ---------------- K8: GEMM2  outs_c = relu( An @ hwc ) ----------------
// grid (8 mt, 8 bpair, 40 gr), 256 thr (4 waves 2x2), tile 128x128, BK=64
__global__ __launch_bounds__(256) void gemm_c_kernel(
    const u16* __restrict__ An,     // [40][1024][1024]
    const u16* __restrict__ hwcT,   // [4][1024 rows=(b,e)][NPAD]
    u16* __restrict__ outs0)
{
  __shared__ __align__(1024) u16 lds[16384];   // A 8192 + B 8192

  const int tid = threadIdx.x, lane = tid & 63, wid = tid >> 6;
  const int mt = blockIdx.x, by = blockIdx.y, gr = blockIdx.z;
  const int g = gr / Rr, r = gr % Rr;
  const int m0 = mt * 128;
  const int wrow0 = (wid >> 1) * 64, wcol0 = (wid & 1) * 64;
  const int lr = lane & 15, hi = lane >> 4;
  const int kbhi = hi * 16;

  const u16* Ap = An + (size_t)gr * (MP * SP) + (size_t)m0 * SP;
  const u16* Bp = hwcT + (size_t)(g * 1024 + by * 128) * NPAD + r * Ss;

  fvec4 acc[4][4];
  #pragma unroll
  for (int i = 0; i < 4; ++i)
    #pragma unroll
    for (int j = 0; j < 4; ++j) acc[i][j] = (fvec4){0.f, 0.f, 0.f, 0.f};

  #pragma unroll 1
  for (int kt = 0; kt < 16; ++kt) {
    const int kk = kt * 64;
    __syncthreads();
    stage_tile(Ap + kk, SP, 16, lds, wid, lane);
    stage_tile(Bp + kk, NPAD, 16, lds + 8192, wid, lane);
    __syncthreads();
    #pragma unroll
    for (int ks = 0; ks < 2; ++ks) {
      bfrag8 a[4], bb[4];
      #pragma unroll
      for (int mfi = 0; mfi < 4; ++mfi) a[mfi] = ldsw(lds, wrow0 + mfi * 16 + lr, ks * 64 + kbhi);
      #pragma unroll
      for (int nfi = 0; nfi < 4; ++nfi) bb[nfi] = ldsw(lds + 8192, wcol0 + nfi * 16 + lr, ks * 64 + kbhi);
      #pragma unroll
      for (int mfi = 0; mfi < 4; ++mfi)
        #pragma unroll
        for (int nfi = 0; nfi < 4; ++nfi)
          acc[mfi][nfi] = __builtin_amdgcn_mfma_f32_16x16x32_bf16(a[mfi], bb[nfi], acc[mfi][nfi], 0, 0, 0);
    }
  }

  // direct store: relu, col -> (b, e)
  #pragma unroll
  for (int mfi = 0; mfi < 4; ++mfi)
    #pragma unroll
    for (int nfi = 0; nfi < 4; ++nfi)
      #pragma unroll
      for (int j = 0; j < 4; ++j) {
        int srow = m0 + wrow0 + mfi * 16 + hi * 4 + j;
        if (srow < Ss) {
          int col = wcol0 + nfi * 16 + lr;
          int bb2 = by * 2 + (col >> 6), e = col & 63;
          int n = r * Ss + srow;
          outs0[(((size_t)g * Bc + bb2) * Nn + n) * 64 + e] = f2bf(fmaxf(acc[mfi][nfi][j], 0.f));
        }
      }
}

// ---------------- K5: MFMA attention combine (MODE 0=U sigmoid, 1=R cand, 2=C final) -----
// grid 2500, 256 thr; one 64-row tile per block
template <int MODE>
__global__ __launch_bounds__(256) void attn_kernel(
    const u16* __restrict__ outs,      // [4][160000][64] bf16 (relu'd)
    const float* __restrict__ rs,      // [160000][2]
    const u16* __restrict__ a1wT,      // [64 e][256 k] bf16 (pre-transposed)
    const u16* __restrict__ a1wb,      // [258][64] bf16 (rows 256/257 used)
    const float* __restrict__ a1b, const float* __restrict__ a2w, const float* __restrict__ a2b,
    const float* __restrict__ h_prev, const u16* __restrict__ usig_in,
    u16* __restrict__ usig_out, u16* __restrict__ candb_out, float* __restrict__ out_final)
{
  __shared__ __align__(16) u16 Hs[16384];      // [64 row][256 k], XOR-swizzled
  __shared__ __align__(16) float alpha_s[256]; // [64 row][4 g]

  const int tid = threadIdx.x, lane = tid & 63, w = tid >> 6;
  const int lr16 = lane & 15, hi4 = lane >> 4;
  const int lk = hi4 << 3;
  const int w16 = w * 16;
  const int row0 = blockIdx.x * 64;

  // stage H: Hs[ri][g*64+e] = outs[g][row0+ri][e] (swizzled, b128)
  #pragma unroll
  for (int j = 0; j < 8; ++j) {
    int c = tid + j * 256;              // 2048 chunks of 8 u16
    int g = c >> 9, rem = c & 511, ri = rem >> 3, e8 = rem & 7;
    bfrag8 v = *(const bfrag8*)&outs[((size_t)g * (Bc * Nn) + row0 + ri) * 64 + e8 * 8];
    *(bfrag8*)&Hs[(ri * 256 + g * 64 + e8 * 8) ^ ((ri & 7) << 3)] = v;
  }

  // hoisted per-lane constants (cols e' = ef*16+lr16)
  float a1b_v[4], w256v[4], w257v[4], a2w_l[16], a2b_v[4];
  #pragma unroll
  for (int ef = 0; ef < 4; ++ef) {
    int e = ef * 16 + lr16;
    a1b_v[ef] = a1b[e];
    w256v[ef] = bf2f(a1wb[256 * 64 + e]);
    w257v[ef] = bf2f(a1wb[257 * 64 + e]);
    #pragma unroll
    for (int g = 0; g < 4; ++g) a2w_l[ef * 4 + g] = a2w[e * 4 + g];
  }
  #pragma unroll
  for (int g = 0; g < 4; ++g) a2b_v[g] = a2b[g];
  __syncthreads();

  // z-GEMM: wave w -> rows w16..w16+15, all 64 e-cols; B frags from global (L2-hot)
  fvec4 zacc[4];
  #pragma unroll
  for (int ef = 0; ef < 4; ++ef) zacc[ef] = (fvec4){0.f, 0.f, 0.f, 0.f};
  #pragma unroll
  for (int ks = 0; ks < 8; ++ks) {
    bfrag8 af = *(const bfrag8*)&Hs[((w16 + lr16) * 256 + ks * 32 + lk) ^ ((lr16 & 7) << 3)];
    #pragma unroll
    for (int ef = 0; ef < 4; ++ef) {
      bfrag8 bf = *(const bfrag8*)&a1wT[(ef * 16 + lr16) * 256 + ks * 32 + lk];
      zacc[ef] = __builtin_amdgcn_mfma_f32_16x16x32_bf16(af, bf, zacc[ef], 0, 0, 0);
    }
  }

  // rs + relu + a2w partial products; rows handled: w16 + hi4*4 + j
  float r0[4], r1[4];
  #pragma unroll
  for (int j = 0; j < 4; ++j) {
    int rrow = row0 + w16 + hi4 * 4 + j;
    float2 rv = *(const float2*)(rs + (size_t)rrow * 2);
    r0[j] = rv.x; r1[j] = rv.y;
  }
  float pj[16];                          // [j][g]
  #pragma unroll
  for (int i = 0; i < 16; ++i) pj[i] = 0.f;
  #pragma unroll
  for (int ef = 0; ef < 4; ++ef)
    #pragma unroll
    for (int j = 0; j < 4; ++j) {
      float zv = zacc[ef][j] + a1b_v[ef] + r0[j] * w256v[ef] + r1[j] * w257v[ef];
      zv = fmaxf(zv, 0.f);
      #pragma unroll
      for (int g = 0; g < 4; ++g) pj[j * 4 + g] = fmaf(zv, a2w_l[ef * 4 + g], pj[j * 4 + g]);
    }
  #pragma unroll
  for (int off = 1; off <= 8; off <<= 1)
    #pragma unroll
    for (int i = 0; i < 16; ++i) pj[i] += __shfl_xor(pj[i], off);

  // softmax + bias; lanes lr16<4 write alpha
  #pragma unroll
  for (int j = 0; j < 4; ++j) {
    float p0 = pj[j * 4 + 0] + a2b_v[0], p1 = pj[j * 4 + 1] + a2b_v[1];
    float p2 = pj[j * 4 + 2] + a2b_v[2], p3 = pj[j * 4 + 3] + a2b_v[3];
    float m = fmaxf(fmaxf(p0, p1), fmaxf(p2, p3));
    float e0 = __expf(p0 - m), e1 = __expf(p1 - m), e2 = __expf(p2 - m), e3 = __expf(p3 - m);
    if (r1[j] > 0.5f) { e0 *= 1.1f; e1 *= 1.1f; e2 *= 1.1f; e3 *= 2.0f; }
    float inv = 1.f / (e0 + e1 + e2 + e3);
    if (lr16 < 4) {
      float esel = (lr16 == 0) ? e0 : (lr16 == 1) ? e1 : (lr16 == 2) ? e2 : e3;
      alpha_s[(w16 + hi4 * 4 + j) * 4 + lr16] = esel * inv;
    }
  }

  // comb + epilogue: lane = e, rows w16..w16+15 (same wave)
  #pragma unroll 1
  for (int rr = 0; rr < 16; ++rr) {
    int lrow = w16 + rr;
    float4 av = *(const float4*)&alpha_s[lrow * 4];
    int sw = (lrow & 7) << 3, base = lrow * 256;
    float cmb = av.x * bf2f(Hs[(base + lane) ^ sw])
              + av.y * bf2f(Hs[(base + 64 + lane) ^ sw])
              + av.z * bf2f(Hs[(base + 128 + lane) ^ sw])
              + av.w * bf2f(Hs[(base + 192 + lane) ^ sw]);
    size_t row = (size_t)(row0 + lrow);
    size_t gi = row * 64 + lane;
    if (MODE == 0) {
      usig_out[gi] = f2bf(1.f / (1.f + __expf(-cmb)));
    } else if (MODE == 1) {
      candb_out[row * 96 + 32 + lane] = f2bf(cmb * h_prev[gi]);
    } else {
      float u = bf2f(usig_in[gi]), hp = h_prev[gi];
      out_final[gi] = u * tanhf(cmb) + (1.f - u) * hp;
    }
  }
}

// ---------------- host ----------------
extern "C" void kernel_launch(void* const* d_in, const int* in_sizes, int n_in,
                              void* d_out, int out_size, void* d_ws, size_t ws_size,
                              hipStream_t stream) {
  (void)in_sizes; (void)n_in; (void)out_size; (void)ws_size;
  const float* x_t    = (const float*)d_in[0];
  const float* h_prev = (const float*)d_in[1];
  const float* A      = (const float*)d_in[2];
  const float* rs     = (const float*)d_in[3];
  const float* W_u    = (const float*)d_in[4];
  const float* a1w_u  = (const float*)d_in[5];
  const float* a1b_u  = (const float*)d_in[6];
  const float* a2w_u  = (const float*)d_in[7];
  const float* a2b_u  = (const float*)d_in[8];
  const float* W_r    = (const float*)d_in[9];
  const float* a1w_r  = (const float*)d_in[10];
  const float* a1b_r  = (const float*)d_in[11];
  const float* a2w_r  = (const float*)d_in[12];
  const float* a2b_r  = (const float*)d_in[13];
  const float* W_c    = (const float*)d_in[14];
  const float* a1w_c  = (const float*)d_in[15];
  const float* a1b_c  = (const float*)d_in[16];
  const float* a2w_c  = (const float*)d_in[17];
  const float* a2b_c  = (const float*)d_in[18];
  float* out = (float*)d_out;

  char* ws = (char*)d_ws;
  // ws layout (bytes)
  const size_t AN_OFF    = 0;            // 40*1024*1024*2      = 83,886,080
  const size_t DIS_OFF   = 83886080;     // 160,000
  const size_t INPT_OFF  = 84046080;     // 16*96*10048*2       = 30,867,456
  const size_t OUTSU_OFF = 114913536;    // 81,920,000
  const size_t OUTSR_OFF = 196833536;    // max(outsR, hwcT)    = 82,313,216
  const size_t USIG_OFF  = 279146752;    // 20,480,000 (bf16)
  const size_t CANDB_OFF = 299626752;    // 160000*96*2         = 30,720,000
  const size_t WT_OFF    = 330346752;    // 147,456
  const size_t A1WB_OFF  = 330494208;    // 99,072
  const size_t A1WT_OFF  = 330593280;    // 98,304  -> end 330,691,584

  u16* An    = (u16*)(ws + AN_OFF);
  float* dis = (float*)(ws + DIS_OFF);
  u16* inpT  = (u16*)(ws + INPT_OFF);
  u16* outsU = (u16*)(ws + OUTSU_OFF);
  u16* outsR = (u16*)(ws + OUTSR_OFF);
  u16* hwcT  = (u16*)(ws + OUTSR_OFF);   // overlays outsR (dead after attn_R)
  u16* outsC = outsU;                    // overlays outsU (dead after attn_U)
  u16* usig  = (u16*)(ws + USIG_OFF);
  u16* candb = (u16*)(ws + CANDB_OFF);
  u16* Wt    = (u16*)(ws + WT_OFF);
  u16* a1wb  = (u16*)(ws + A1WB_OFF);
  u16* a1wT  = (u16*)(ws + A1WT_OFF);

  prep_weights_kernel<<<674, 256, 0, stream>>>(W_u, W_r, W_c, a1w_u, a1w_r, a1w_c, Wt, a1wb, a1wT);
  rowsum_kernel<<<10000, 256, 0, stream>>>(A, dis);
  build_an_kernel<<<40960, 256, 0, stream>>>(A, dis, An);
  prep_inpT_kernel<<<dim3(157, 16), 256, 0, stream>>>(x_t, h_prev, inpT, candb);

  gemm_uv_kernel<<<dim3(8, 8, 40), 256, 0, stream>>>(An, inpT, Wt, outsU, outsR);

  attn_kernel<0><<<2500, 256, 0, stream>>>(outsU, rs, a1wT, a1wb, a1b_u, a2w_u, a2b_u,
                                           nullptr, nullptr, usig, nullptr, nullptr);
  attn_kernel<1><<<2500, 256, 0, stream>>>(outsR, rs, a1wT + 16384, a1wb + 16512, a1b_r, a2w_r, a2b_r,
                                           h_prev, nullptr, nullptr, candb, nullptr);

  cand_proj_kernel<<<dim3(157, 16), 256, 0, stream>>>(candb, Wt, hwcT);
  gemm_c_kernel<<<dim3(8, 8, 40), 256, 0, stream>>>(An, hwcT, outsC);

  attn_kernel<2><<<2500, 256, 0, stream>>>(outsC, rs, a1wT + 32768, a1wb + 33024, a1b_c, a2w_c, a2b_c,
                                           h_prev, usig, nullptr, nullptr, out);
}